// Round 3
// baseline (7961.621 us; speedup 1.0000x reference)
//
#include <hip/hip_runtime.h>

// ---------------------------------------------------------------------------
// 3-layer GCN + linear head.  N=50000 nodes, E=800000 edges, D=128.
// CSR build via counting sort (single u64 atomic per edge), then
// [fp32 pipelined GEMM] x4 and [wave-per-node CSR aggregation, 8 gathers in
// flight] x3.
// ---------------------------------------------------------------------------

#define D 128
#define FXS 16777216.0f   // 2^24 fixed-point scale for edge-weight sums

// ---- init packed degree/count ---------------------------------------------
__global__ __launch_bounds__(256) void k_init(unsigned long long* packed, int N) {
    int i = blockIdx.x * 256 + threadIdx.x;
    if (i < N) packed[i] = 0ull;
}

// ---- pass 1: one u64 atomic per edge; old count -> per-edge CSR slot ------
__global__ __launch_bounds__(256) void k_edge_pass1(const int* __restrict__ dst,
                                                    const float* __restrict__ w,
                                                    unsigned long long* packed,
                                                    int* __restrict__ loc, int E) {
    int e = blockIdx.x * 256 + threadIdx.x;
    if (e < E) {
        int d = dst[e];
        unsigned long long add =
            (1ull << 32) | (unsigned long long)__float2uint_rn(w[e] * FXS);
        unsigned long long old = atomicAdd(&packed[d], add);
        loc[e] = (int)(old >> 32);
    }
}

// ---- dinv = rsqrt(1 + fxsum); extract integer count for the scan ----------
__global__ __launch_bounds__(256) void k_dinv(const unsigned long long* __restrict__ packed,
                                              float* dinv, int* cnt, int N) {
    int i = blockIdx.x * 256 + threadIdx.x;
    if (i < N) {
        unsigned long long p = packed[i];
        float deg = 1.0f + (float)(unsigned int)(p & 0xffffffffull) * (1.0f / FXS);
        dinv[i] = rsqrtf(deg);
        cnt[i] = (int)(p >> 32);
    }
}

// ---- block-wide exclusive scan helper (256 threads) -----------------------
__device__ inline int block_exscan_256(int v) {
    int tid = threadIdx.x;
    int lane = tid & 63, wv = tid >> 6;
    int incl = v;
#pragma unroll
    for (int d = 1; d < 64; d <<= 1) {
        int n = __shfl_up(incl, d, 64);
        if (lane >= d) incl += n;
    }
    __shared__ int wsum[4];
    if (lane == 63) wsum[wv] = incl;
    __syncthreads();
    int woff = 0;
#pragma unroll
    for (int j = 0; j < 4; j++) woff += (j < wv) ? wsum[j] : 0;
    return woff + incl - v;
}

__global__ __launch_bounds__(256) void k_scan_a(const int* __restrict__ cnt,
                                                int* bsum, int N) {
    int i = blockIdx.x * 256 + threadIdx.x;
    int v = (i < N) ? cnt[i] : 0;
#pragma unroll
    for (int d = 32; d; d >>= 1) v += __shfl_down(v, d, 64);
    __shared__ int ws4[4];
    int lane = threadIdx.x & 63, wv = threadIdx.x >> 6;
    if (lane == 0) ws4[wv] = v;
    __syncthreads();
    if (threadIdx.x == 0) bsum[blockIdx.x] = ws4[0] + ws4[1] + ws4[2] + ws4[3];
}

__global__ __launch_bounds__(256) void k_scan_b(const int* __restrict__ bsum,
                                                int* boff, int nb) {
    int tid = threadIdx.x;
    int v = (tid < nb) ? bsum[tid] : 0;
    int ex = block_exscan_256(v);
    if (tid < nb) boff[tid] = ex;
}

__global__ __launch_bounds__(256) void k_scan_c(const int* __restrict__ cnt,
                                                const int* __restrict__ boff,
                                                int* rp, int N, int E) {
    int i = blockIdx.x * 256 + threadIdx.x;
    int v = (i < N) ? cnt[i] : 0;
    int ex = block_exscan_256(v);
    if (i < N) rp[i] = boff[blockIdx.x] + ex;
    if (i == 0) rp[N] = E;
}

// ---- CSR fill: NO atomics; packed (col,val) as float2 ---------------------
__global__ __launch_bounds__(256) void k_fill(const int* __restrict__ ei,
                                              const float* __restrict__ w,
                                              const float* __restrict__ dinv,
                                              const int* __restrict__ rp,
                                              const int* __restrict__ loc,
                                              float2* ev, int E) {
    int e = blockIdx.x * 256 + threadIdx.x;
    if (e < E) {
        int s = ei[e];
        int d = ei[E + e];
        int p = rp[d] + loc[e];
        ev[p] = make_float2(__int_as_float(s), dinv[s] * w[e] * dinv[d]);
    }
}

// ---- fp32 pipelined GEMM: C[N,128] = A[N,128] @ W[128,128] (+bias) --------
// 64 rows/block, 256 threads, 4x8 register tile per thread.
// Double-buffered LDS; next k-tile global loads issued before the FMA block
// so global latency overlaps compute. One __syncthreads per tile.
__global__ __launch_bounds__(256) void k_gemm(const float* __restrict__ A,
                                              const float* __restrict__ W,
                                              const float* __restrict__ bias,
                                              float* __restrict__ C, int N) {
    __shared__ float At[2][32][68];   // transposed A tile [k][row]
    __shared__ float Wt[2][32][128];  // W tile [k][col]
    int tid = threadIdx.x;
    int row0 = blockIdx.x * 64;
    int tx = tid & 15, ty = tid >> 4;

    float4 wreg[4];
    float4 areg[2];

    int wr[4], wc[4], ar[2], ac[2];
#pragma unroll
    for (int j = 0; j < 4; j++) {
        int e = tid * 4 + j * 1024;
        wr[j] = e >> 7; wc[j] = e & 127;
    }
#pragma unroll
    for (int j = 0; j < 2; j++) {
        int e = tid * 4 + j * 1024;
        ar[j] = e >> 5; ac[j] = e & 31;
    }

    auto load_tile = [&](int k0) {
#pragma unroll
        for (int j = 0; j < 4; j++)
            wreg[j] = *(const float4*)&W[(k0 + wr[j]) * 128 + wc[j]];
#pragma unroll
        for (int j = 0; j < 2; j++) {
            int grow = row0 + ar[j];
            areg[j] = (grow < N) ? *(const float4*)&A[(size_t)grow * 128 + k0 + ac[j]]
                                 : make_float4(0.f, 0.f, 0.f, 0.f);
        }
    };
    auto store_tile = [&](int b) {
#pragma unroll
        for (int j = 0; j < 4; j++)
            *(float4*)&Wt[b][wr[j]][wc[j]] = wreg[j];
#pragma unroll
        for (int j = 0; j < 2; j++) {
            At[b][ac[j] + 0][ar[j]] = areg[j].x;
            At[b][ac[j] + 1][ar[j]] = areg[j].y;
            At[b][ac[j] + 2][ar[j]] = areg[j].z;
            At[b][ac[j] + 3][ar[j]] = areg[j].w;
        }
    };

    float acc[4][8];
#pragma unroll
    for (int r = 0; r < 4; r++)
#pragma unroll
        for (int c = 0; c < 8; c++) acc[r][c] = 0.0f;

    load_tile(0);
    store_tile(0);
    __syncthreads();

#pragma unroll
    for (int t = 0; t < 4; t++) {
        if (t < 3) load_tile((t + 1) * 32);   // prefetch: no wait until store
        int b = t & 1;
#pragma unroll
        for (int kk = 0; kk < 32; kk++) {
            float4 a  = *(const float4*)&At[b][kk][ty * 4];
            float4 w0 = *(const float4*)&Wt[b][kk][tx * 4];
            float4 w1 = *(const float4*)&Wt[b][kk][64 + tx * 4];
            float av[4] = {a.x, a.y, a.z, a.w};
            float wv[8] = {w0.x, w0.y, w0.z, w0.w, w1.x, w1.y, w1.z, w1.w};
#pragma unroll
            for (int r = 0; r < 4; r++)
#pragma unroll
                for (int c = 0; c < 8; c++)
                    acc[r][c] = fmaf(av[r], wv[c], acc[r][c]);
        }
        if (t < 3) {
            store_tile(b ^ 1);   // other buffer: safe, everyone is past it
            __syncthreads();
        }
    }

    float bv[8] = {0, 0, 0, 0, 0, 0, 0, 0};
    if (bias) {
        float4 b0 = *(const float4*)&bias[tx * 4];
        float4 b1 = *(const float4*)&bias[64 + tx * 4];
        bv[0] = b0.x; bv[1] = b0.y; bv[2] = b0.z; bv[3] = b0.w;
        bv[4] = b1.x; bv[5] = b1.y; bv[6] = b1.z; bv[7] = b1.w;
    }
#pragma unroll
    for (int r = 0; r < 4; r++) {
        int row = row0 + ty * 4 + r;
        if (row < N) {
            float4 o0 = make_float4(acc[r][0] + bv[0], acc[r][1] + bv[1],
                                    acc[r][2] + bv[2], acc[r][3] + bv[3]);
            float4 o1 = make_float4(acc[r][4] + bv[4], acc[r][5] + bv[5],
                                    acc[r][6] + bv[6], acc[r][7] + bv[7]);
            *(float4*)&C[(size_t)row * 128 + tx * 4] = o0;
            *(float4*)&C[(size_t)row * 128 + 64 + tx * 4] = o1;
        }
    }
}

// ---- aggregation: one wave per node; half-wave per edge slot, float4/lane,
// unroll-4 => 8 gather rows in flight per wave. --------------------------
__global__ __launch_bounds__(256) void k_agg(const float* __restrict__ h,
                                             const int* __restrict__ rp,
                                             const float2* __restrict__ ev,
                                             const float* __restrict__ dinv,
                                             const float* __restrict__ bias,
                                             float* __restrict__ out,
                                             int N, int relu) {
    int wave = blockIdx.x * 4 + (threadIdx.x >> 6);
    if (wave >= N) return;
    int lane = threadIdx.x & 63;
    int half = lane >> 5;
    int sl = lane & 31;
    int i = wave;

    float4 acc = make_float4(0.f, 0.f, 0.f, 0.f);
    int e0 = rp[i], e1 = rp[i + 1];
    int e = e0;

#define EDGE_FMA(EIDX)                                                   \
    {                                                                    \
        float2 p = ev[EIDX];                                             \
        int c = __float_as_int(p.x);                                     \
        float v = p.y;                                                   \
        float4 hh = *(const float4*)&h[(size_t)c * D + sl * 4];          \
        acc.x = fmaf(v, hh.x, acc.x); acc.y = fmaf(v, hh.y, acc.y);      \
        acc.z = fmaf(v, hh.z, acc.z); acc.w = fmaf(v, hh.w, acc.w);      \
    }

    for (; e + 8 <= e1; e += 8) {
        float2 p0 = ev[e + half];
        float2 p1 = ev[e + 2 + half];
        float2 p2 = ev[e + 4 + half];
        float2 p3 = ev[e + 6 + half];
        int c0 = __float_as_int(p0.x), c1 = __float_as_int(p1.x);
        int c2 = __float_as_int(p2.x), c3 = __float_as_int(p3.x);
        float4 h0 = *(const float4*)&h[(size_t)c0 * D + sl * 4];
        float4 h1 = *(const float4*)&h[(size_t)c1 * D + sl * 4];
        float4 h2 = *(const float4*)&h[(size_t)c2 * D + sl * 4];
        float4 h3 = *(const float4*)&h[(size_t)c3 * D + sl * 4];
        acc.x = fmaf(p0.y, h0.x, acc.x); acc.y = fmaf(p0.y, h0.y, acc.y);
        acc.z = fmaf(p0.y, h0.z, acc.z); acc.w = fmaf(p0.y, h0.w, acc.w);
        acc.x = fmaf(p1.y, h1.x, acc.x); acc.y = fmaf(p1.y, h1.y, acc.y);
        acc.z = fmaf(p1.y, h1.z, acc.z); acc.w = fmaf(p1.y, h1.w, acc.w);
        acc.x = fmaf(p2.y, h2.x, acc.x); acc.y = fmaf(p2.y, h2.y, acc.y);
        acc.z = fmaf(p2.y, h2.z, acc.z); acc.w = fmaf(p2.y, h2.w, acc.w);
        acc.x = fmaf(p3.y, h3.x, acc.x); acc.y = fmaf(p3.y, h3.y, acc.y);
        acc.z = fmaf(p3.y, h3.z, acc.z); acc.w = fmaf(p3.y, h3.w, acc.w);
    }
    if (e + 4 <= e1) {
        float2 p0 = ev[e + half];
        float2 p1 = ev[e + 2 + half];
        int c0 = __float_as_int(p0.x), c1 = __float_as_int(p1.x);
        float4 h0 = *(const float4*)&h[(size_t)c0 * D + sl * 4];
        float4 h1 = *(const float4*)&h[(size_t)c1 * D + sl * 4];
        acc.x = fmaf(p0.y, h0.x, acc.x); acc.y = fmaf(p0.y, h0.y, acc.y);
        acc.z = fmaf(p0.y, h0.z, acc.z); acc.w = fmaf(p0.y, h0.w, acc.w);
        acc.x = fmaf(p1.y, h1.x, acc.x); acc.y = fmaf(p1.y, h1.y, acc.y);
        acc.z = fmaf(p1.y, h1.z, acc.z); acc.w = fmaf(p1.y, h1.w, acc.w);
        e += 4;
    }
    if (e + 2 <= e1) {
        EDGE_FMA(e + half);
        e += 2;
    }
    if (e < e1 && half == 0) {
        EDGE_FMA(e);
    }
#undef EDGE_FMA

    // combine the two half-wave partial sums (lane l <-> lane l^32)
    acc.x += __shfl_xor(acc.x, 32, 64);
    acc.y += __shfl_xor(acc.y, 32, 64);
    acc.z += __shfl_xor(acc.z, 32, 64);
    acc.w += __shfl_xor(acc.w, 32, 64);

    if (half == 0) {
        float di = dinv[i];
        float self = di * di;
        float4 hi = *(const float4*)&h[(size_t)i * D + sl * 4];
        float4 b  = *(const float4*)&bias[sl * 4];
        float4 o;
        o.x = acc.x + b.x + self * hi.x;
        o.y = acc.y + b.y + self * hi.y;
        o.z = acc.z + b.z + self * hi.z;
        o.w = acc.w + b.w + self * hi.w;
        if (relu) {
            o.x = fmaxf(o.x, 0.f); o.y = fmaxf(o.y, 0.f);
            o.z = fmaxf(o.z, 0.f); o.w = fmaxf(o.w, 0.f);
        }
        *(float4*)&out[(size_t)i * D + sl * 4] = o;
    }
}

// ---------------------------------------------------------------------------
extern "C" void kernel_launch(void* const* d_in, const int* in_sizes, int n_in,
                              void* d_out, int out_size, void* d_ws, size_t ws_size,
                              hipStream_t stream) {
    const float* x  = (const float*)d_in[0];
    const int*   ei = (const int*)d_in[1];     // [2,E]: src row then dst row
    const float* ew = (const float*)d_in[2];
    const float* W1 = (const float*)d_in[3];
    const float* b1 = (const float*)d_in[4];
    const float* W2 = (const float*)d_in[5];
    const float* b2 = (const float*)d_in[6];
    const float* W3 = (const float*)d_in[7];
    const float* b3 = (const float*)d_in[8];
    const float* Wl = (const float*)d_in[9];
    const float* bl = (const float*)d_in[10];

    int N = in_sizes[0] / D;    // 50000
    int E = in_sizes[2];        // 800000

    char* ws = (char*)d_ws;
    size_t off = 0;
    auto alloc = [&](size_t bytes) {
        void* p = ws + off;
        off = (off + bytes + 255) & ~(size_t)255;
        return p;
    };
    unsigned long long* packed = (unsigned long long*)alloc((size_t)N * 8);
    float*  dinv = (float*)alloc((size_t)N * 4);
    int*    cnt  = (int*)  alloc((size_t)N * 4);
    int*    bsum = (int*)  alloc(1024);
    int*    boff = (int*)  alloc(1024);
    int*    rp   = (int*)  alloc((size_t)(N + 1) * 4);
    int*    loc  = (int*)  alloc((size_t)E * 4);
    float2* ev   = (float2*)alloc((size_t)E * 8);
    float*  bufB = (float*)alloc((size_t)N * D * 4);
    float*  bufA = (float*)d_out;                        // ping-pong with d_out

    int nbN = (N + 255) / 256;      // 196 (<= 256 for k_scan_b)
    int nbE = (E + 255) / 256;

    k_init<<<nbN, 256, 0, stream>>>(packed, N);
    k_edge_pass1<<<nbE, 256, 0, stream>>>(ei + E, ew, packed, loc, E);
    k_dinv<<<nbN, 256, 0, stream>>>(packed, dinv, cnt, N);
    k_scan_a<<<nbN, 256, 0, stream>>>(cnt, bsum, N);
    k_scan_b<<<1, 256, 0, stream>>>(bsum, boff, nbN);
    k_scan_c<<<nbN, 256, 0, stream>>>(cnt, boff, rp, N, E);
    k_fill<<<nbE, 256, 0, stream>>>(ei, ew, dinv, rp, loc, ev, E);

    int gg = (N + 63) / 64;     // GEMM blocks
    int ga = (N + 3) / 4;       // agg blocks (4 waves each)

    k_gemm<<<gg, 256, 0, stream>>>(x,    W1, nullptr, bufA, N);
    k_agg <<<ga, 256, 0, stream>>>(bufA, rp, ev, dinv, b1, bufB, N, 1);
    k_gemm<<<gg, 256, 0, stream>>>(bufB, W2, nullptr, bufA, N);
    k_agg <<<ga, 256, 0, stream>>>(bufA, rp, ev, dinv, b2, bufB, N, 1);
    k_gemm<<<gg, 256, 0, stream>>>(bufB, W3, nullptr, bufA, N);
    k_agg <<<ga, 256, 0, stream>>>(bufA, rp, ev, dinv, b3, bufB, N, 0);
    k_gemm<<<gg, 256, 0, stream>>>(bufB, Wl, bl, (float*)d_out, N);
}

// Round 4
// 446.965 us; speedup vs baseline: 17.8126x; 17.8126x over previous
//
#include <hip/hip_runtime.h>

// ---------------------------------------------------------------------------
// 3-layer GCN + linear head.  N=50000 nodes, E=800000 edges, D=128.
// CSR build via counting sort (single u64 atomic per edge), then
// [fp32 GEMM, single-LDS-buffer + register prefetch] x4 and
// [wave-per-node CSR aggregation, 8 gathers in flight] x3.
// ---------------------------------------------------------------------------

#define D 128
#define FXS 16777216.0f   // 2^24 fixed-point scale for edge-weight sums

// ---- init packed degree/count ---------------------------------------------
__global__ __launch_bounds__(256) void k_init(unsigned long long* packed, int N) {
    int i = blockIdx.x * 256 + threadIdx.x;
    if (i < N) packed[i] = 0ull;
}

// ---- pass 1: one u64 atomic per edge; old count -> per-edge CSR slot ------
__global__ __launch_bounds__(256) void k_edge_pass1(const int* __restrict__ dst,
                                                    const float* __restrict__ w,
                                                    unsigned long long* packed,
                                                    int* __restrict__ loc, int E) {
    int e = blockIdx.x * 256 + threadIdx.x;
    if (e < E) {
        int d = dst[e];
        unsigned long long add =
            (1ull << 32) | (unsigned long long)__float2uint_rn(w[e] * FXS);
        unsigned long long old = atomicAdd(&packed[d], add);
        loc[e] = (int)(old >> 32);
    }
}

// ---- dinv = rsqrt(1 + fxsum); extract integer count for the scan ----------
__global__ __launch_bounds__(256) void k_dinv(const unsigned long long* __restrict__ packed,
                                              float* dinv, int* cnt, int N) {
    int i = blockIdx.x * 256 + threadIdx.x;
    if (i < N) {
        unsigned long long p = packed[i];
        float deg = 1.0f + (float)(unsigned int)(p & 0xffffffffull) * (1.0f / FXS);
        dinv[i] = rsqrtf(deg);
        cnt[i] = (int)(p >> 32);
    }
}

// ---- block-wide exclusive scan helper (256 threads) -----------------------
__device__ inline int block_exscan_256(int v) {
    int tid = threadIdx.x;
    int lane = tid & 63, wv = tid >> 6;
    int incl = v;
#pragma unroll
    for (int d = 1; d < 64; d <<= 1) {
        int n = __shfl_up(incl, d, 64);
        if (lane >= d) incl += n;
    }
    __shared__ int wsum[4];
    if (lane == 63) wsum[wv] = incl;
    __syncthreads();
    int woff = 0;
#pragma unroll
    for (int j = 0; j < 4; j++) woff += (j < wv) ? wsum[j] : 0;
    return woff + incl - v;
}

__global__ __launch_bounds__(256) void k_scan_a(const int* __restrict__ cnt,
                                                int* bsum, int N) {
    int i = blockIdx.x * 256 + threadIdx.x;
    int v = (i < N) ? cnt[i] : 0;
#pragma unroll
    for (int d = 32; d; d >>= 1) v += __shfl_down(v, d, 64);
    __shared__ int ws4[4];
    int lane = threadIdx.x & 63, wv = threadIdx.x >> 6;
    if (lane == 0) ws4[wv] = v;
    __syncthreads();
    if (threadIdx.x == 0) bsum[blockIdx.x] = ws4[0] + ws4[1] + ws4[2] + ws4[3];
}

__global__ __launch_bounds__(256) void k_scan_b(const int* __restrict__ bsum,
                                                int* boff, int nb) {
    int tid = threadIdx.x;
    int v = (tid < nb) ? bsum[tid] : 0;
    int ex = block_exscan_256(v);
    if (tid < nb) boff[tid] = ex;
}

__global__ __launch_bounds__(256) void k_scan_c(const int* __restrict__ cnt,
                                                const int* __restrict__ boff,
                                                int* rp, int N, int E) {
    int i = blockIdx.x * 256 + threadIdx.x;
    int v = (i < N) ? cnt[i] : 0;
    int ex = block_exscan_256(v);
    if (i < N) rp[i] = boff[blockIdx.x] + ex;
    if (i == 0) rp[N] = E;
}

// ---- CSR fill: NO atomics; packed (col,val) as float2 ---------------------
__global__ __launch_bounds__(256) void k_fill(const int* __restrict__ ei,
                                              const float* __restrict__ w,
                                              const float* __restrict__ dinv,
                                              const int* __restrict__ rp,
                                              const int* __restrict__ loc,
                                              float2* ev, int E) {
    int e = blockIdx.x * 256 + threadIdx.x;
    if (e < E) {
        int s = ei[e];
        int d = ei[E + e];
        int p = rp[d] + loc[e];
        ev[p] = make_float2(__int_as_float(s), dinv[s] * w[e] * dinv[d]);
    }
}

// ---- fp32 GEMM: C[N,128] = A[N,128] @ W[128,128] (+bias) ------------------
// 64 rows/block, 256 threads, 4x8 register tile per thread.
// SINGLE LDS buffer (25 KB). Register prefetch of the next k-tile is issued
// before the FMA block; `#pragma unroll 1` on the tile loop keeps the body
// singular so VGPRs stay ~100 (round-3 full unroll spilled at 256 VGPR).
__global__ __launch_bounds__(256) void k_gemm(const float* __restrict__ A,
                                              const float* __restrict__ W,
                                              const float* __restrict__ bias,
                                              float* __restrict__ C, int N) {
    __shared__ float At[32][68];   // transposed A tile [k][row]
    __shared__ float Wt[32][128];  // W tile [k][col]
    int tid = threadIdx.x;
    int row0 = blockIdx.x * 64;
    int tx = tid & 15, ty = tid >> 4;

    // staging coordinates (computed once)
    int wr0 = (tid * 4) >> 7,          wc0 = (tid * 4) & 127;
    int wr1 = (tid * 4 + 1024) >> 7,   wc1 = (tid * 4 + 1024) & 127;
    int wr2 = (tid * 4 + 2048) >> 7,   wc2 = (tid * 4 + 2048) & 127;
    int wr3 = (tid * 4 + 3072) >> 7,   wc3 = (tid * 4 + 3072) & 127;
    int ar0 = (tid * 4) >> 5,          ac0 = (tid * 4) & 31;
    int ar1 = (tid * 4 + 1024) >> 5,   ac1 = (tid * 4 + 1024) & 31;
    int ga0 = row0 + ar0, ga1 = row0 + ar1;

    float4 w0r, w1r, w2r, w3r, a0r, a1r;

    // prefetch tile 0
    w0r = *(const float4*)&W[wr0 * 128 + wc0];
    w1r = *(const float4*)&W[wr1 * 128 + wc1];
    w2r = *(const float4*)&W[wr2 * 128 + wc2];
    w3r = *(const float4*)&W[wr3 * 128 + wc3];
    a0r = (ga0 < N) ? *(const float4*)&A[(size_t)ga0 * 128 + ac0]
                    : make_float4(0.f, 0.f, 0.f, 0.f);
    a1r = (ga1 < N) ? *(const float4*)&A[(size_t)ga1 * 128 + ac1]
                    : make_float4(0.f, 0.f, 0.f, 0.f);

    float acc[4][8];
#pragma unroll
    for (int r = 0; r < 4; r++)
#pragma unroll
        for (int c = 0; c < 8; c++) acc[r][c] = 0.0f;

#pragma unroll 1
    for (int t = 0; t < 4; t++) {
        // store prefetched tile to LDS
        *(float4*)&Wt[wr0][wc0] = w0r;
        *(float4*)&Wt[wr1][wc1] = w1r;
        *(float4*)&Wt[wr2][wc2] = w2r;
        *(float4*)&Wt[wr3][wc3] = w3r;
        At[ac0 + 0][ar0] = a0r.x; At[ac0 + 1][ar0] = a0r.y;
        At[ac0 + 2][ar0] = a0r.z; At[ac0 + 3][ar0] = a0r.w;
        At[ac1 + 0][ar1] = a1r.x; At[ac1 + 1][ar1] = a1r.y;
        At[ac1 + 2][ar1] = a1r.z; At[ac1 + 3][ar1] = a1r.w;
        __syncthreads();

        // issue next tile's global loads (results not needed until next store)
        if (t < 3) {
            int k0 = (t + 1) * 32;
            w0r = *(const float4*)&W[(k0 + wr0) * 128 + wc0];
            w1r = *(const float4*)&W[(k0 + wr1) * 128 + wc1];
            w2r = *(const float4*)&W[(k0 + wr2) * 128 + wc2];
            w3r = *(const float4*)&W[(k0 + wr3) * 128 + wc3];
            a0r = (ga0 < N) ? *(const float4*)&A[(size_t)ga0 * 128 + k0 + ac0]
                            : make_float4(0.f, 0.f, 0.f, 0.f);
            a1r = (ga1 < N) ? *(const float4*)&A[(size_t)ga1 * 128 + k0 + ac1]
                            : make_float4(0.f, 0.f, 0.f, 0.f);
        }

#pragma unroll
        for (int kk = 0; kk < 32; kk++) {
            float4 a  = *(const float4*)&At[kk][ty * 4];
            float4 u0 = *(const float4*)&Wt[kk][tx * 4];
            float4 u1 = *(const float4*)&Wt[kk][64 + tx * 4];
            float av[4] = {a.x, a.y, a.z, a.w};
            float wv[8] = {u0.x, u0.y, u0.z, u0.w, u1.x, u1.y, u1.z, u1.w};
#pragma unroll
            for (int r = 0; r < 4; r++)
#pragma unroll
                for (int c = 0; c < 8; c++)
                    acc[r][c] = fmaf(av[r], wv[c], acc[r][c]);
        }
        __syncthreads();
    }

    float bv[8] = {0, 0, 0, 0, 0, 0, 0, 0};
    if (bias) {
        float4 b0 = *(const float4*)&bias[tx * 4];
        float4 b1 = *(const float4*)&bias[64 + tx * 4];
        bv[0] = b0.x; bv[1] = b0.y; bv[2] = b0.z; bv[3] = b0.w;
        bv[4] = b1.x; bv[5] = b1.y; bv[6] = b1.z; bv[7] = b1.w;
    }
#pragma unroll
    for (int r = 0; r < 4; r++) {
        int row = row0 + ty * 4 + r;
        if (row < N) {
            float4 o0 = make_float4(acc[r][0] + bv[0], acc[r][1] + bv[1],
                                    acc[r][2] + bv[2], acc[r][3] + bv[3]);
            float4 o1 = make_float4(acc[r][4] + bv[4], acc[r][5] + bv[5],
                                    acc[r][6] + bv[6], acc[r][7] + bv[7]);
            *(float4*)&C[(size_t)row * 128 + tx * 4] = o0;
            *(float4*)&C[(size_t)row * 128 + 64 + tx * 4] = o1;
        }
    }
}

// ---- aggregation: one wave per node; half-wave per edge slot, float4/lane,
// unroll-4 => 8 gather rows in flight per wave. --------------------------
__global__ __launch_bounds__(256) void k_agg(const float* __restrict__ h,
                                             const int* __restrict__ rp,
                                             const float2* __restrict__ ev,
                                             const float* __restrict__ dinv,
                                             const float* __restrict__ bias,
                                             float* __restrict__ out,
                                             int N, int relu) {
    int wave = blockIdx.x * 4 + (threadIdx.x >> 6);
    if (wave >= N) return;
    int lane = threadIdx.x & 63;
    int half = lane >> 5;
    int sl = lane & 31;
    int i = wave;

    float4 acc = make_float4(0.f, 0.f, 0.f, 0.f);
    int e0 = rp[i], e1 = rp[i + 1];
    int e = e0;

#define EDGE_FMA(EIDX)                                                   \
    {                                                                    \
        float2 p = ev[EIDX];                                             \
        int c = __float_as_int(p.x);                                     \
        float v = p.y;                                                   \
        float4 hh = *(const float4*)&h[(size_t)c * D + sl * 4];          \
        acc.x = fmaf(v, hh.x, acc.x); acc.y = fmaf(v, hh.y, acc.y);      \
        acc.z = fmaf(v, hh.z, acc.z); acc.w = fmaf(v, hh.w, acc.w);      \
    }

    for (; e + 8 <= e1; e += 8) {
        float2 p0 = ev[e + half];
        float2 p1 = ev[e + 2 + half];
        float2 p2 = ev[e + 4 + half];
        float2 p3 = ev[e + 6 + half];
        int c0 = __float_as_int(p0.x), c1 = __float_as_int(p1.x);
        int c2 = __float_as_int(p2.x), c3 = __float_as_int(p3.x);
        float4 h0 = *(const float4*)&h[(size_t)c0 * D + sl * 4];
        float4 h1 = *(const float4*)&h[(size_t)c1 * D + sl * 4];
        float4 h2 = *(const float4*)&h[(size_t)c2 * D + sl * 4];
        float4 h3 = *(const float4*)&h[(size_t)c3 * D + sl * 4];
        acc.x = fmaf(p0.y, h0.x, acc.x); acc.y = fmaf(p0.y, h0.y, acc.y);
        acc.z = fmaf(p0.y, h0.z, acc.z); acc.w = fmaf(p0.y, h0.w, acc.w);
        acc.x = fmaf(p1.y, h1.x, acc.x); acc.y = fmaf(p1.y, h1.y, acc.y);
        acc.z = fmaf(p1.y, h1.z, acc.z); acc.w = fmaf(p1.y, h1.w, acc.w);
        acc.x = fmaf(p2.y, h2.x, acc.x); acc.y = fmaf(p2.y, h2.y, acc.y);
        acc.z = fmaf(p2.y, h2.z, acc.z); acc.w = fmaf(p2.y, h2.w, acc.w);
        acc.x = fmaf(p3.y, h3.x, acc.x); acc.y = fmaf(p3.y, h3.y, acc.y);
        acc.z = fmaf(p3.y, h3.z, acc.z); acc.w = fmaf(p3.y, h3.w, acc.w);
    }
    if (e + 4 <= e1) {
        float2 p0 = ev[e + half];
        float2 p1 = ev[e + 2 + half];
        int c0 = __float_as_int(p0.x), c1 = __float_as_int(p1.x);
        float4 h0 = *(const float4*)&h[(size_t)c0 * D + sl * 4];
        float4 h1 = *(const float4*)&h[(size_t)c1 * D + sl * 4];
        acc.x = fmaf(p0.y, h0.x, acc.x); acc.y = fmaf(p0.y, h0.y, acc.y);
        acc.z = fmaf(p0.y, h0.z, acc.z); acc.w = fmaf(p0.y, h0.w, acc.w);
        acc.x = fmaf(p1.y, h1.x, acc.x); acc.y = fmaf(p1.y, h1.y, acc.y);
        acc.z = fmaf(p1.y, h1.z, acc.z); acc.w = fmaf(p1.y, h1.w, acc.w);
        e += 4;
    }
    if (e + 2 <= e1) {
        EDGE_FMA(e + half);
        e += 2;
    }
    if (e < e1 && half == 0) {
        EDGE_FMA(e);
    }
#undef EDGE_FMA

    // combine the two half-wave partial sums (lane l <-> lane l^32)
    acc.x += __shfl_xor(acc.x, 32, 64);
    acc.y += __shfl_xor(acc.y, 32, 64);
    acc.z += __shfl_xor(acc.z, 32, 64);
    acc.w += __shfl_xor(acc.w, 32, 64);

    if (half == 0) {
        float di = dinv[i];
        float self = di * di;
        float4 hi = *(const float4*)&h[(size_t)i * D + sl * 4];
        float4 b  = *(const float4*)&bias[sl * 4];
        float4 o;
        o.x = acc.x + b.x + self * hi.x;
        o.y = acc.y + b.y + self * hi.y;
        o.z = acc.z + b.z + self * hi.z;
        o.w = acc.w + b.w + self * hi.w;
        if (relu) {
            o.x = fmaxf(o.x, 0.f); o.y = fmaxf(o.y, 0.f);
            o.z = fmaxf(o.z, 0.f); o.w = fmaxf(o.w, 0.f);
        }
        *(float4*)&out[(size_t)i * D + sl * 4] = o;
    }
}

// ---------------------------------------------------------------------------
extern "C" void kernel_launch(void* const* d_in, const int* in_sizes, int n_in,
                              void* d_out, int out_size, void* d_ws, size_t ws_size,
                              hipStream_t stream) {
    const float* x  = (const float*)d_in[0];
    const int*   ei = (const int*)d_in[1];     // [2,E]: src row then dst row
    const float* ew = (const float*)d_in[2];
    const float* W1 = (const float*)d_in[3];
    const float* b1 = (const float*)d_in[4];
    const float* W2 = (const float*)d_in[5];
    const float* b2 = (const float*)d_in[6];
    const float* W3 = (const float*)d_in[7];
    const float* b3 = (const float*)d_in[8];
    const float* Wl = (const float*)d_in[9];
    const float* bl = (const float*)d_in[10];

    int N = in_sizes[0] / D;    // 50000
    int E = in_sizes[2];        // 800000

    char* ws = (char*)d_ws;
    size_t off = 0;
    auto alloc = [&](size_t bytes) {
        void* p = ws + off;
        off = (off + bytes + 255) & ~(size_t)255;
        return p;
    };
    unsigned long long* packed = (unsigned long long*)alloc((size_t)N * 8);
    float*  dinv = (float*)alloc((size_t)N * 4);
    int*    cnt  = (int*)  alloc((size_t)N * 4);
    int*    bsum = (int*)  alloc(1024);
    int*    boff = (int*)  alloc(1024);
    int*    rp   = (int*)  alloc((size_t)(N + 1) * 4);
    int*    loc  = (int*)  alloc((size_t)E * 4);
    float2* ev   = (float2*)alloc((size_t)E * 8);
    float*  bufB = (float*)alloc((size_t)N * D * 4);
    float*  bufA = (float*)d_out;                        // ping-pong with d_out

    int nbN = (N + 255) / 256;      // 196 (<= 256 for k_scan_b)
    int nbE = (E + 255) / 256;

    k_init<<<nbN, 256, 0, stream>>>(packed, N);
    k_edge_pass1<<<nbE, 256, 0, stream>>>(ei + E, ew, packed, loc, E);
    k_dinv<<<nbN, 256, 0, stream>>>(packed, dinv, cnt, N);
    k_scan_a<<<nbN, 256, 0, stream>>>(cnt, bsum, N);
    k_scan_b<<<1, 256, 0, stream>>>(bsum, boff, nbN);
    k_scan_c<<<nbN, 256, 0, stream>>>(cnt, boff, rp, N, E);
    k_fill<<<nbE, 256, 0, stream>>>(ei, ew, dinv, rp, loc, ev, E);

    int gg = (N + 63) / 64;     // GEMM blocks
    int ga = (N + 3) / 4;       // agg blocks (4 waves each)

    k_gemm<<<gg, 256, 0, stream>>>(x,    W1, nullptr, bufA, N);
    k_agg <<<ga, 256, 0, stream>>>(bufA, rp, ev, dinv, b1, bufB, N, 1);
    k_gemm<<<gg, 256, 0, stream>>>(bufB, W2, nullptr, bufA, N);
    k_agg <<<ga, 256, 0, stream>>>(bufA, rp, ev, dinv, b2, bufB, N, 1);
    k_gemm<<<gg, 256, 0, stream>>>(bufB, W3, nullptr, bufA, N);
    k_agg <<<ga, 256, 0, stream>>>(bufA, rp, ev, dinv, b3, bufB, N, 0);
    k_gemm<<<gg, 256, 0, stream>>>(bufB, Wl, bl, (float*)d_out, N);
}

// Round 5
// 378.223 us; speedup vs baseline: 21.0500x; 1.1817x over previous
//
#include <hip/hip_runtime.h>
#include <hip/hip_fp16.h>

// ---------------------------------------------------------------------------
// 3-layer GCN + linear head.  N=50000 nodes, E=800000 edges, D=128.
// CSR build via counting sort (single u64 atomic per edge), then
// [fp32 GEMM 128x128 tile, 8x8/thread, fp16 shadow output] x4 and
// [wave-per-node CSR aggregation gathering fp16 rows] x3.
// ---------------------------------------------------------------------------

#define D 128
#define FXS 16777216.0f   // 2^24 fixed-point scale for edge-weight sums

// ---- init packed degree/count ---------------------------------------------
__global__ __launch_bounds__(256) void k_init(unsigned long long* packed, int N) {
    int i = blockIdx.x * 256 + threadIdx.x;
    if (i < N) packed[i] = 0ull;
}

// ---- pass 1: one u64 atomic per edge; old count -> per-edge CSR slot ------
__global__ __launch_bounds__(256) void k_edge_pass1(const int* __restrict__ dst,
                                                    const float* __restrict__ w,
                                                    unsigned long long* packed,
                                                    int* __restrict__ loc, int E) {
    int e = blockIdx.x * 256 + threadIdx.x;
    if (e < E) {
        int d = dst[e];
        unsigned long long add =
            (1ull << 32) | (unsigned long long)__float2uint_rn(w[e] * FXS);
        unsigned long long old = atomicAdd(&packed[d], add);
        loc[e] = (int)(old >> 32);
    }
}

// ---- dinv = rsqrt(1 + fxsum); extract integer count for the scan ----------
__global__ __launch_bounds__(256) void k_dinv(const unsigned long long* __restrict__ packed,
                                              float* dinv, int* cnt, int N) {
    int i = blockIdx.x * 256 + threadIdx.x;
    if (i < N) {
        unsigned long long p = packed[i];
        float deg = 1.0f + (float)(unsigned int)(p & 0xffffffffull) * (1.0f / FXS);
        dinv[i] = rsqrtf(deg);
        cnt[i] = (int)(p >> 32);
    }
}

// ---- block-wide exclusive scan helper (256 threads) -----------------------
__device__ inline int block_exscan_256(int v) {
    int tid = threadIdx.x;
    int lane = tid & 63, wv = tid >> 6;
    int incl = v;
#pragma unroll
    for (int d = 1; d < 64; d <<= 1) {
        int n = __shfl_up(incl, d, 64);
        if (lane >= d) incl += n;
    }
    __shared__ int wsum[4];
    if (lane == 63) wsum[wv] = incl;
    __syncthreads();
    int woff = 0;
#pragma unroll
    for (int j = 0; j < 4; j++) woff += (j < wv) ? wsum[j] : 0;
    return woff + incl - v;
}

__global__ __launch_bounds__(256) void k_scan_a(const int* __restrict__ cnt,
                                                int* bsum, int N) {
    int i = blockIdx.x * 256 + threadIdx.x;
    int v = (i < N) ? cnt[i] : 0;
#pragma unroll
    for (int d = 32; d; d >>= 1) v += __shfl_down(v, d, 64);
    __shared__ int ws4[4];
    int lane = threadIdx.x & 63, wv = threadIdx.x >> 6;
    if (lane == 0) ws4[wv] = v;
    __syncthreads();
    if (threadIdx.x == 0) bsum[blockIdx.x] = ws4[0] + ws4[1] + ws4[2] + ws4[3];
}

__global__ __launch_bounds__(256) void k_scan_b(const int* __restrict__ bsum,
                                                int* boff, int nb) {
    int tid = threadIdx.x;
    int v = (tid < nb) ? bsum[tid] : 0;
    int ex = block_exscan_256(v);
    if (tid < nb) boff[tid] = ex;
}

__global__ __launch_bounds__(256) void k_scan_c(const int* __restrict__ cnt,
                                                const int* __restrict__ boff,
                                                int* rp, int N, int E) {
    int i = blockIdx.x * 256 + threadIdx.x;
    int v = (i < N) ? cnt[i] : 0;
    int ex = block_exscan_256(v);
    if (i < N) rp[i] = boff[blockIdx.x] + ex;
    if (i == 0) rp[N] = E;
}

// ---- CSR fill: NO atomics; packed (col,val) as float2 ---------------------
__global__ __launch_bounds__(256) void k_fill(const int* __restrict__ ei,
                                              const float* __restrict__ w,
                                              const float* __restrict__ dinv,
                                              const int* __restrict__ rp,
                                              const int* __restrict__ loc,
                                              float2* ev, int E) {
    int e = blockIdx.x * 256 + threadIdx.x;
    if (e < E) {
        int s = ei[e];
        int d = ei[E + e];
        int p = rp[d] + loc[e];
        ev[p] = make_float2(__int_as_float(s), dinv[s] * w[e] * dinv[d]);
    }
}

// ---- fp32 GEMM: C[N,128] = A[N,128] @ W[128,128] (+bias), fp16 shadow -----
// 128 rows/block, 256 threads, 8x8 register tile per thread, BK=16.
// LDS reads: 64 B per 64 FMAs = 1 B/FMA (vs 1.5 for the old 4x8 tile).
// `#pragma unroll 1` on the tile loop: round-3 full unroll spilled (256 VGPR,
// 2.3 GB scratch fetch/dispatch).
__global__ __launch_bounds__(256) void k_gemm(const float* __restrict__ A,
                                              const float* __restrict__ W,
                                              const float* __restrict__ bias,
                                              float* __restrict__ C,
                                              __half* __restrict__ C16, int N) {
    __shared__ float At[16][132];   // transposed A tile [k][row], pad 128->132
    __shared__ float Wt[16][128];   // W tile [k][col]
    int tid = threadIdx.x;
    int row0 = blockIdx.x * 128;
    int tx = tid & 15, ty = tid >> 4;   // tx: col group, ty: 8-row group

    // staging coords: 512 float4 slots each for A and W, 2 per thread
    int af0 = tid * 2, af1 = tid * 2 + 1;
    int ar0 = af0 >> 2, as0 = (af0 & 3) * 4;   // A: row, k-seg
    int ar1 = af1 >> 2, as1 = (af1 & 3) * 4;
    int wk0 = af0 >> 5, wc0 = (af0 & 31) * 4;  // W: k-row, col
    int wk1 = af1 >> 5, wc1 = (af1 & 31) * 4;
    int ga0 = row0 + ar0, ga1 = row0 + ar1;

    float4 a0r, a1r, w0r, w1r;
    // prefetch tile 0
    w0r = *(const float4*)&W[wk0 * 128 + wc0];
    w1r = *(const float4*)&W[wk1 * 128 + wc1];
    a0r = (ga0 < N) ? *(const float4*)&A[(size_t)ga0 * 128 + as0]
                    : make_float4(0.f, 0.f, 0.f, 0.f);
    a1r = (ga1 < N) ? *(const float4*)&A[(size_t)ga1 * 128 + as1]
                    : make_float4(0.f, 0.f, 0.f, 0.f);

    float acc[8][8];
#pragma unroll
    for (int r = 0; r < 8; r++)
#pragma unroll
        for (int c = 0; c < 8; c++) acc[r][c] = 0.0f;

#pragma unroll 1
    for (int t = 0; t < 8; t++) {
        *(float4*)&Wt[wk0][wc0] = w0r;
        *(float4*)&Wt[wk1][wc1] = w1r;
        At[as0 + 0][ar0] = a0r.x; At[as0 + 1][ar0] = a0r.y;
        At[as0 + 2][ar0] = a0r.z; At[as0 + 3][ar0] = a0r.w;
        At[as1 + 0][ar1] = a1r.x; At[as1 + 1][ar1] = a1r.y;
        At[as1 + 2][ar1] = a1r.z; At[as1 + 3][ar1] = a1r.w;
        __syncthreads();

        if (t < 7) {   // issue next tile's loads; results used at next store
            int k0 = (t + 1) * 16;
            w0r = *(const float4*)&W[(k0 + wk0) * 128 + wc0];
            w1r = *(const float4*)&W[(k0 + wk1) * 128 + wc1];
            a0r = (ga0 < N) ? *(const float4*)&A[(size_t)ga0 * 128 + k0 + as0]
                            : make_float4(0.f, 0.f, 0.f, 0.f);
            a1r = (ga1 < N) ? *(const float4*)&A[(size_t)ga1 * 128 + k0 + as1]
                            : make_float4(0.f, 0.f, 0.f, 0.f);
        }

#pragma unroll
        for (int kk = 0; kk < 16; kk++) {
            float4 p0 = *(const float4*)&At[kk][ty * 8];
            float4 p1 = *(const float4*)&At[kk][ty * 8 + 4];
            float4 u0 = *(const float4*)&Wt[kk][tx * 4];
            float4 u1 = *(const float4*)&Wt[kk][64 + tx * 4];
            float av[8] = {p0.x, p0.y, p0.z, p0.w, p1.x, p1.y, p1.z, p1.w};
            float wv[8] = {u0.x, u0.y, u0.z, u0.w, u1.x, u1.y, u1.z, u1.w};
#pragma unroll
            for (int r = 0; r < 8; r++)
#pragma unroll
                for (int c = 0; c < 8; c++)
                    acc[r][c] = fmaf(av[r], wv[c], acc[r][c]);
        }
        __syncthreads();
    }

    float bv[8] = {0, 0, 0, 0, 0, 0, 0, 0};
    if (bias) {
        float4 b0 = *(const float4*)&bias[tx * 4];
        float4 b1 = *(const float4*)&bias[64 + tx * 4];
        bv[0] = b0.x; bv[1] = b0.y; bv[2] = b0.z; bv[3] = b0.w;
        bv[4] = b1.x; bv[5] = b1.y; bv[6] = b1.z; bv[7] = b1.w;
    }
#pragma unroll
    for (int r = 0; r < 8; r++) {
        int row = row0 + ty * 8 + r;
        if (row < N) {
            float o[8];
#pragma unroll
            for (int c = 0; c < 8; c++) o[c] = acc[r][c] + bv[c];
            *(float4*)&C[(size_t)row * 128 + tx * 4]      = make_float4(o[0], o[1], o[2], o[3]);
            *(float4*)&C[(size_t)row * 128 + 64 + tx * 4] = make_float4(o[4], o[5], o[6], o[7]);
            if (C16) {
                union { __half2 h2[2]; uint2 u; } q0, q1;
                q0.h2[0] = __float22half2_rn(make_float2(o[0], o[1]));
                q0.h2[1] = __float22half2_rn(make_float2(o[2], o[3]));
                q1.h2[0] = __float22half2_rn(make_float2(o[4], o[5]));
                q1.h2[1] = __float22half2_rn(make_float2(o[6], o[7]));
                *(uint2*)&C16[(size_t)row * 128 + tx * 4]      = q0.u;
                *(uint2*)&C16[(size_t)row * 128 + 64 + tx * 4] = q1.u;
            }
        }
    }
}

// ---- aggregation: one wave per node; quarter-wave (16 lanes) per edge -----
// lane group g=lane>>4 handles edge e+g; lane sl=lane&15 covers features
// sl*8..sl*8+7 as one uint4 (8 fp16) gather = 16 B/lane, 256 B/edge.
// Main loop: 16 edges in flight per wave. Self term + accum in fp32.
__global__ __launch_bounds__(256) void k_agg(const float* __restrict__ h,
                                             const __half* __restrict__ h16,
                                             const int* __restrict__ rp,
                                             const float2* __restrict__ ev,
                                             const float* __restrict__ dinv,
                                             const float* __restrict__ bias,
                                             float* __restrict__ out,
                                             int N, int relu) {
    int wave = blockIdx.x * 4 + (threadIdx.x >> 6);
    if (wave >= N) return;
    int lane = threadIdx.x & 63;
    int g = lane >> 4;
    int sl = lane & 15;
    int i = wave;

    float acc[8];
#pragma unroll
    for (int j = 0; j < 8; j++) acc[j] = 0.f;

    int e0 = rp[i], e1 = rp[i + 1];
    int e = e0;

#define GFMA(Q, V)                                                        \
    {                                                                     \
        union { uint4 u; __half2 h2[4]; } U; U.u = (Q);                   \
        float2 f0 = __half22float2(U.h2[0]);                              \
        float2 f1 = __half22float2(U.h2[1]);                              \
        float2 f2 = __half22float2(U.h2[2]);                              \
        float2 f3 = __half22float2(U.h2[3]);                              \
        acc[0] = fmaf(V, f0.x, acc[0]); acc[1] = fmaf(V, f0.y, acc[1]);   \
        acc[2] = fmaf(V, f1.x, acc[2]); acc[3] = fmaf(V, f1.y, acc[3]);   \
        acc[4] = fmaf(V, f2.x, acc[4]); acc[5] = fmaf(V, f2.y, acc[5]);   \
        acc[6] = fmaf(V, f3.x, acc[6]); acc[7] = fmaf(V, f3.y, acc[7]);   \
    }

    for (; e + 16 <= e1; e += 16) {
        float2 pA = ev[e + g];
        float2 pB = ev[e + 4 + g];
        float2 pC = ev[e + 8 + g];
        float2 pD = ev[e + 12 + g];
        uint4 qA = *(const uint4*)&h16[(size_t)__float_as_int(pA.x) * D + sl * 8];
        uint4 qB = *(const uint4*)&h16[(size_t)__float_as_int(pB.x) * D + sl * 8];
        uint4 qC = *(const uint4*)&h16[(size_t)__float_as_int(pC.x) * D + sl * 8];
        uint4 qD = *(const uint4*)&h16[(size_t)__float_as_int(pD.x) * D + sl * 8];
        GFMA(qA, pA.y); GFMA(qB, pB.y); GFMA(qC, pC.y); GFMA(qD, pD.y);
    }
    if (e + 8 <= e1) {
        float2 pA = ev[e + g];
        float2 pB = ev[e + 4 + g];
        uint4 qA = *(const uint4*)&h16[(size_t)__float_as_int(pA.x) * D + sl * 8];
        uint4 qB = *(const uint4*)&h16[(size_t)__float_as_int(pB.x) * D + sl * 8];
        GFMA(qA, pA.y); GFMA(qB, pB.y);
        e += 8;
    }
    if (e + 4 <= e1) {
        float2 pA = ev[e + g];
        uint4 qA = *(const uint4*)&h16[(size_t)__float_as_int(pA.x) * D + sl * 8];
        GFMA(qA, pA.y);
        e += 4;
    }
    if (e + g < e1) {
        float2 pA = ev[e + g];
        uint4 qA = *(const uint4*)&h16[(size_t)__float_as_int(pA.x) * D + sl * 8];
        GFMA(qA, pA.y);
    }
#undef GFMA

    // fold the 4 quarter-wave partials (lane ^16, ^32)
#pragma unroll
    for (int j = 0; j < 8; j++) {
        acc[j] += __shfl_xor(acc[j], 16, 64);
        acc[j] += __shfl_xor(acc[j], 32, 64);
    }

    if (g == 0) {
        float di = dinv[i];
        float self = di * di;
        float4 s0 = *(const float4*)&h[(size_t)i * D + sl * 8];
        float4 s1 = *(const float4*)&h[(size_t)i * D + sl * 8 + 4];
        float4 b0 = *(const float4*)&bias[sl * 8];
        float4 b1 = *(const float4*)&bias[sl * 8 + 4];
        float o[8];
        o[0] = acc[0] + b0.x + self * s0.x;
        o[1] = acc[1] + b0.y + self * s0.y;
        o[2] = acc[2] + b0.z + self * s0.z;
        o[3] = acc[3] + b0.w + self * s0.w;
        o[4] = acc[4] + b1.x + self * s1.x;
        o[5] = acc[5] + b1.y + self * s1.y;
        o[6] = acc[6] + b1.z + self * s1.z;
        o[7] = acc[7] + b1.w + self * s1.w;
        if (relu) {
#pragma unroll
            for (int j = 0; j < 8; j++) o[j] = fmaxf(o[j], 0.f);
        }
        *(float4*)&out[(size_t)i * D + sl * 8]     = make_float4(o[0], o[1], o[2], o[3]);
        *(float4*)&out[(size_t)i * D + sl * 8 + 4] = make_float4(o[4], o[5], o[6], o[7]);
    }
}

// ---------------------------------------------------------------------------
extern "C" void kernel_launch(void* const* d_in, const int* in_sizes, int n_in,
                              void* d_out, int out_size, void* d_ws, size_t ws_size,
                              hipStream_t stream) {
    const float* x  = (const float*)d_in[0];
    const int*   ei = (const int*)d_in[1];     // [2,E]: src row then dst row
    const float* ew = (const float*)d_in[2];
    const float* W1 = (const float*)d_in[3];
    const float* b1 = (const float*)d_in[4];
    const float* W2 = (const float*)d_in[5];
    const float* b2 = (const float*)d_in[6];
    const float* W3 = (const float*)d_in[7];
    const float* b3 = (const float*)d_in[8];
    const float* Wl = (const float*)d_in[9];
    const float* bl = (const float*)d_in[10];

    int N = in_sizes[0] / D;    // 50000
    int E = in_sizes[2];        // 800000

    char* ws = (char*)d_ws;
    size_t off = 0;
    auto alloc = [&](size_t bytes) {
        void* p = ws + off;
        off = (off + bytes + 255) & ~(size_t)255;
        return p;
    };
    unsigned long long* packed = (unsigned long long*)alloc((size_t)N * 8);
    float*  dinv = (float*)alloc((size_t)N * 4);
    int*    cnt  = (int*)  alloc((size_t)N * 4);
    int*    bsum = (int*)  alloc(1024);
    int*    boff = (int*)  alloc(1024);
    int*    rp   = (int*)  alloc((size_t)(N + 1) * 4);
    int*    loc  = (int*)  alloc((size_t)E * 4);
    float2* ev   = (float2*)alloc((size_t)E * 8);
    float*  bufB = (float*)alloc((size_t)N * D * 4);
    __half* h16  = (__half*)alloc((size_t)N * D * 2);
    float*  bufA = (float*)d_out;                        // ping-pong with d_out

    int nbN = (N + 255) / 256;      // 196 (<= 256 for k_scan_b)
    int nbE = (E + 255) / 256;

    k_init<<<nbN, 256, 0, stream>>>(packed, N);
    k_edge_pass1<<<nbE, 256, 0, stream>>>(ei + E, ew, packed, loc, E);
    k_dinv<<<nbN, 256, 0, stream>>>(packed, dinv, cnt, N);
    k_scan_a<<<nbN, 256, 0, stream>>>(cnt, bsum, N);
    k_scan_b<<<1, 256, 0, stream>>>(bsum, boff, nbN);
    k_scan_c<<<nbN, 256, 0, stream>>>(cnt, boff, rp, N, E);
    k_fill<<<nbE, 256, 0, stream>>>(ei, ew, dinv, rp, loc, ev, E);

    int gg = (N + 127) / 128;   // GEMM blocks (128 rows each)
    int ga = (N + 3) / 4;       // agg blocks (4 waves each)

    k_gemm<<<gg, 256, 0, stream>>>(x,    W1, nullptr, bufA, h16, N);
    k_agg <<<ga, 256, 0, stream>>>(bufA, h16, rp, ev, dinv, b1, bufB, N, 1);
    k_gemm<<<gg, 256, 0, stream>>>(bufB, W2, nullptr, bufA, h16, N);
    k_agg <<<ga, 256, 0, stream>>>(bufA, h16, rp, ev, dinv, b2, bufB, N, 1);
    k_gemm<<<gg, 256, 0, stream>>>(bufB, W3, nullptr, bufA, h16, N);
    k_agg <<<ga, 256, 0, stream>>>(bufA, h16, rp, ev, dinv, b3, bufB, N, 0);
    k_gemm<<<gg, 256, 0, stream>>>(bufB, Wl, bl, (float*)d_out, nullptr, N);
}

// Round 6
// 309.847 us; speedup vs baseline: 25.6953x; 1.2207x over previous
//
#include <hip/hip_runtime.h>
#include <hip/hip_fp16.h>

// ---------------------------------------------------------------------------
// 3-layer GCN + linear head.  N=50000 nodes, E=800000 edges, D=128.
// CSR build via counting sort (single u64 atomic per edge), then
// [MFMA fp16 GEMM (fp32 accum)] x4 and [wave-per-node fp16 CSR agg] x3.
// All intermediates fp16; fp32 only for accumulation, bias, and final out.
// ---------------------------------------------------------------------------

#define D 128
#define FXS 16777216.0f   // 2^24 fixed-point scale for edge-weight sums

typedef __attribute__((ext_vector_type(8))) _Float16 half8;
typedef __attribute__((ext_vector_type(4))) float floatx4;

// ---- init packed degree/count ---------------------------------------------
__global__ __launch_bounds__(256) void k_init(unsigned long long* packed, int N) {
    int i = blockIdx.x * 256 + threadIdx.x;
    if (i < N) packed[i] = 0ull;
}

// ---- pass 1: one u64 atomic per edge; old count -> per-edge CSR slot ------
__global__ __launch_bounds__(256) void k_edge_pass1(const int* __restrict__ dst,
                                                    const float* __restrict__ w,
                                                    unsigned long long* packed,
                                                    int* __restrict__ loc, int E) {
    int e = blockIdx.x * 256 + threadIdx.x;
    if (e < E) {
        int d = dst[e];
        unsigned long long add =
            (1ull << 32) | (unsigned long long)__float2uint_rn(w[e] * FXS);
        unsigned long long old = atomicAdd(&packed[d], add);
        loc[e] = (int)(old >> 32);
    }
}

// ---- dinv = rsqrt(1 + fxsum); extract integer count for the scan ----------
__global__ __launch_bounds__(256) void k_dinv(const unsigned long long* __restrict__ packed,
                                              float* dinv, int* cnt, int N) {
    int i = blockIdx.x * 256 + threadIdx.x;
    if (i < N) {
        unsigned long long p = packed[i];
        float deg = 1.0f + (float)(unsigned int)(p & 0xffffffffull) * (1.0f / FXS);
        dinv[i] = rsqrtf(deg);
        cnt[i] = (int)(p >> 32);
    }
}

// ---- block-wide exclusive scan helper (256 threads) -----------------------
__device__ inline int block_exscan_256(int v) {
    int tid = threadIdx.x;
    int lane = tid & 63, wv = tid >> 6;
    int incl = v;
#pragma unroll
    for (int d = 1; d < 64; d <<= 1) {
        int n = __shfl_up(incl, d, 64);
        if (lane >= d) incl += n;
    }
    __shared__ int wsum[4];
    if (lane == 63) wsum[wv] = incl;
    __syncthreads();
    int woff = 0;
#pragma unroll
    for (int j = 0; j < 4; j++) woff += (j < wv) ? wsum[j] : 0;
    return woff + incl - v;
}

__global__ __launch_bounds__(256) void k_scan_a(const int* __restrict__ cnt,
                                                int* bsum, int N) {
    int i = blockIdx.x * 256 + threadIdx.x;
    int v = (i < N) ? cnt[i] : 0;
#pragma unroll
    for (int d = 32; d; d >>= 1) v += __shfl_down(v, d, 64);
    __shared__ int ws4[4];
    int lane = threadIdx.x & 63, wv = threadIdx.x >> 6;
    if (lane == 0) ws4[wv] = v;
    __syncthreads();
    if (threadIdx.x == 0) bsum[blockIdx.x] = ws4[0] + ws4[1] + ws4[2] + ws4[3];
}

__global__ __launch_bounds__(256) void k_scan_b(const int* __restrict__ bsum,
                                                int* boff, int nb) {
    int tid = threadIdx.x;
    int v = (tid < nb) ? bsum[tid] : 0;
    int ex = block_exscan_256(v);
    if (tid < nb) boff[tid] = ex;
}

__global__ __launch_bounds__(256) void k_scan_c(const int* __restrict__ cnt,
                                                const int* __restrict__ boff,
                                                int* rp, int N, int E) {
    int i = blockIdx.x * 256 + threadIdx.x;
    int v = (i < N) ? cnt[i] : 0;
    int ex = block_exscan_256(v);
    if (i < N) rp[i] = boff[blockIdx.x] + ex;
    if (i == 0) rp[N] = E;
}

// ---- CSR fill: NO atomics; packed (col,val) as float2 ---------------------
__global__ __launch_bounds__(256) void k_fill(const int* __restrict__ ei,
                                              const float* __restrict__ w,
                                              const float* __restrict__ dinv,
                                              const int* __restrict__ rp,
                                              const int* __restrict__ loc,
                                              float2* ev, int E) {
    int e = blockIdx.x * 256 + threadIdx.x;
    if (e < E) {
        int s = ei[e];
        int d = ei[E + e];
        int p = rp[d] + loc[e];
        ev[p] = make_float2(__int_as_float(s), dinv[s] * w[e] * dinv[d]);
    }
}

// ---- MFMA GEMM: C[N,128] = A[N,128] @ W[128,128] ---------------------------
// 128 rows/block (4 waves x 32 rows), v_mfma_f32_16x16x32_f16, fp32 accum.
// W (fp32 global) staged transposed as fp16 in LDS: Wl[n][k], row pad ->136
// (stride 68 dwords -> 2-way bank aliasing = free). A fragments loaded
// directly from global (A is read exactly once; no LDS round-trip).
// Layouts (m89/m91-verified): A[m=lane&15][k=quad*8+j],
// B[k=quad*8+j][n=lane&15], C/D col=lane&15, row=quad*4+reg.
template <bool A_IS_F32>
__global__ __launch_bounds__(256) void k_gemm_mfma(const void* __restrict__ Aptr,
                                                   const float* __restrict__ W,
                                                   const float* __restrict__ bias,
                                                   float* __restrict__ C32,
                                                   __half* __restrict__ C16, int N) {
    __shared__ _Float16 Wl[128][136];
    int tid = threadIdx.x;

    // stage W^T into LDS as fp16 (coalesced fp32 reads: consecutive tid -> n)
#pragma unroll
    for (int j = 0; j < 64; j++) {
        int e = tid + j * 256;          // 16384 elements
        int k = e >> 7, n = e & 127;
        Wl[n][k] = (_Float16)W[e];
    }
    __syncthreads();

    int wave = tid >> 6, lane = tid & 63;
    int m = lane & 15, q = lane >> 4;
    int R0 = blockIdx.x * 128 + wave * 32;   // row tiles R0, R0+16

    const float*   A32p = (const float*)Aptr;
    const __half*  A16p = (const __half*)Aptr;

    floatx4 acc[2][8];
#pragma unroll
    for (int rt = 0; rt < 2; rt++)
#pragma unroll
        for (int ct = 0; ct < 8; ct++) acc[rt][ct] = (floatx4){0.f, 0.f, 0.f, 0.f};

#pragma unroll
    for (int kk = 0; kk < 4; kk++) {
        half8 a[2];
#pragma unroll
        for (int rt = 0; rt < 2; rt++) {
            int row = R0 + rt * 16 + m;
            half8 t = {0, 0, 0, 0, 0, 0, 0, 0};
            if (row < N) {
                if (A_IS_F32) {
                    const float* p = &A32p[(size_t)row * 128 + kk * 32 + q * 8];
                    float4 f0 = *(const float4*)p;
                    float4 f1 = *(const float4*)(p + 4);
                    t[0] = (_Float16)f0.x; t[1] = (_Float16)f0.y;
                    t[2] = (_Float16)f0.z; t[3] = (_Float16)f0.w;
                    t[4] = (_Float16)f1.x; t[5] = (_Float16)f1.y;
                    t[6] = (_Float16)f1.z; t[7] = (_Float16)f1.w;
                } else {
                    t = *(const half8*)&A16p[(size_t)row * 128 + kk * 32 + q * 8];
                }
            }
            a[rt] = t;
        }
#pragma unroll
        for (int ct = 0; ct < 8; ct++) {
            half8 b = *(const half8*)&Wl[ct * 16 + m][kk * 32 + q * 8];
            acc[0][ct] = __builtin_amdgcn_mfma_f32_16x16x32_f16(a[0], b, acc[0][ct], 0, 0, 0);
            acc[1][ct] = __builtin_amdgcn_mfma_f32_16x16x32_f16(a[1], b, acc[1][ct], 0, 0, 0);
        }
    }

    // epilogue: C/D layout col=lane&15 (=m), row=quad*4+reg
#pragma unroll
    for (int rt = 0; rt < 2; rt++) {
#pragma unroll
        for (int ct = 0; ct < 8; ct++) {
            int col = ct * 16 + m;
            float bcol = (bias != nullptr) ? bias[col] : 0.f;
#pragma unroll
            for (int r = 0; r < 4; r++) {
                int row = R0 + rt * 16 + q * 4 + r;
                if (row < N) {
                    float v = acc[rt][ct][r];
                    if (C16) C16[(size_t)row * 128 + col] = __float2half_rn(v);
                    if (C32) C32[(size_t)row * 128 + col] = v + bcol;
                }
            }
        }
    }
}

// ---- aggregation: one wave per node; quarter-wave (16 lanes) per edge -----
// lane group g=lane>>4 handles edge e+g; lane sl=lane&15 covers features
// sl*8..sl*8+7 as one uint4 (8 fp16) gather. 16 edges in flight per wave.
// fp32 accumulate; fp16 in, fp16 out.
__global__ __launch_bounds__(256) void k_agg(const __half* __restrict__ h16,
                                             const int* __restrict__ rp,
                                             const float2* __restrict__ ev,
                                             const float* __restrict__ dinv,
                                             const float* __restrict__ bias,
                                             __half* __restrict__ out16,
                                             int N, int relu) {
    int wave = blockIdx.x * 4 + (threadIdx.x >> 6);
    if (wave >= N) return;
    int lane = threadIdx.x & 63;
    int g = lane >> 4;
    int sl = lane & 15;
    int i = wave;

    float acc[8];
#pragma unroll
    for (int j = 0; j < 8; j++) acc[j] = 0.f;

    int e0 = rp[i], e1 = rp[i + 1];
    int e = e0;

#define GFMA(Q, V)                                                        \
    {                                                                     \
        union { uint4 u; __half2 h2[4]; } U; U.u = (Q);                   \
        float2 f0 = __half22float2(U.h2[0]);                              \
        float2 f1 = __half22float2(U.h2[1]);                              \
        float2 f2 = __half22float2(U.h2[2]);                              \
        float2 f3 = __half22float2(U.h2[3]);                              \
        acc[0] = fmaf(V, f0.x, acc[0]); acc[1] = fmaf(V, f0.y, acc[1]);   \
        acc[2] = fmaf(V, f1.x, acc[2]); acc[3] = fmaf(V, f1.y, acc[3]);   \
        acc[4] = fmaf(V, f2.x, acc[4]); acc[5] = fmaf(V, f2.y, acc[5]);   \
        acc[6] = fmaf(V, f3.x, acc[6]); acc[7] = fmaf(V, f3.y, acc[7]);   \
    }

    for (; e + 16 <= e1; e += 16) {
        float2 pA = ev[e + g];
        float2 pB = ev[e + 4 + g];
        float2 pC = ev[e + 8 + g];
        float2 pD = ev[e + 12 + g];
        uint4 qA = *(const uint4*)&h16[(size_t)__float_as_int(pA.x) * D + sl * 8];
        uint4 qB = *(const uint4*)&h16[(size_t)__float_as_int(pB.x) * D + sl * 8];
        uint4 qC = *(const uint4*)&h16[(size_t)__float_as_int(pC.x) * D + sl * 8];
        uint4 qD = *(const uint4*)&h16[(size_t)__float_as_int(pD.x) * D + sl * 8];
        GFMA(qA, pA.y); GFMA(qB, pB.y); GFMA(qC, pC.y); GFMA(qD, pD.y);
    }
    if (e + 8 <= e1) {
        float2 pA = ev[e + g];
        float2 pB = ev[e + 4 + g];
        uint4 qA = *(const uint4*)&h16[(size_t)__float_as_int(pA.x) * D + sl * 8];
        uint4 qB = *(const uint4*)&h16[(size_t)__float_as_int(pB.x) * D + sl * 8];
        GFMA(qA, pA.y); GFMA(qB, pB.y);
        e += 8;
    }
    if (e + 4 <= e1) {
        float2 pA = ev[e + g];
        uint4 qA = *(const uint4*)&h16[(size_t)__float_as_int(pA.x) * D + sl * 8];
        GFMA(qA, pA.y);
        e += 4;
    }
    if (e + g < e1) {
        float2 pA = ev[e + g];
        uint4 qA = *(const uint4*)&h16[(size_t)__float_as_int(pA.x) * D + sl * 8];
        GFMA(qA, pA.y);
    }
#undef GFMA

    // fold the 4 quarter-wave partials (lane ^16, ^32)
#pragma unroll
    for (int j = 0; j < 8; j++) {
        acc[j] += __shfl_xor(acc[j], 16, 64);
        acc[j] += __shfl_xor(acc[j], 32, 64);
    }

    if (g == 0) {
        float di = dinv[i];
        float self = di * di;
        union { uint4 u; __half2 h2[4]; } S;
        S.u = *(const uint4*)&h16[(size_t)i * D + sl * 8];
        float2 s0 = __half22float2(S.h2[0]);
        float2 s1 = __half22float2(S.h2[1]);
        float2 s2 = __half22float2(S.h2[2]);
        float2 s3 = __half22float2(S.h2[3]);
        float4 b0 = *(const float4*)&bias[sl * 8];
        float4 b1 = *(const float4*)&bias[sl * 8 + 4];
        float o[8];
        o[0] = acc[0] + b0.x + self * s0.x;
        o[1] = acc[1] + b0.y + self * s0.y;
        o[2] = acc[2] + b0.z + self * s1.x;
        o[3] = acc[3] + b0.w + self * s1.y;
        o[4] = acc[4] + b1.x + self * s2.x;
        o[5] = acc[5] + b1.y + self * s2.y;
        o[6] = acc[6] + b1.z + self * s3.x;
        o[7] = acc[7] + b1.w + self * s3.y;
        if (relu) {
#pragma unroll
            for (int j = 0; j < 8; j++) o[j] = fmaxf(o[j], 0.f);
        }
        union { uint4 u; __half2 h2[4]; } O;
        O.h2[0] = __float22half2_rn(make_float2(o[0], o[1]));
        O.h2[1] = __float22half2_rn(make_float2(o[2], o[3]));
        O.h2[2] = __float22half2_rn(make_float2(o[4], o[5]));
        O.h2[3] = __float22half2_rn(make_float2(o[6], o[7]));
        *(uint4*)&out16[(size_t)i * D + sl * 8] = O.u;
    }
}

// ---------------------------------------------------------------------------
extern "C" void kernel_launch(void* const* d_in, const int* in_sizes, int n_in,
                              void* d_out, int out_size, void* d_ws, size_t ws_size,
                              hipStream_t stream) {
    const float* x  = (const float*)d_in[0];
    const int*   ei = (const int*)d_in[1];     // [2,E]: src row then dst row
    const float* ew = (const float*)d_in[2];
    const float* W1 = (const float*)d_in[3];
    const float* b1 = (const float*)d_in[4];
    const float* W2 = (const float*)d_in[5];
    const float* b2 = (const float*)d_in[6];
    const float* W3 = (const float*)d_in[7];
    const float* b3 = (const float*)d_in[8];
    const float* Wl = (const float*)d_in[9];
    const float* bl = (const float*)d_in[10];

    int N = in_sizes[0] / D;    // 50000
    int E = in_sizes[2];        // 800000

    char* ws = (char*)d_ws;
    size_t off = 0;
    auto alloc = [&](size_t bytes) {
        void* p = ws + off;
        off = (off + bytes + 255) & ~(size_t)255;
        return p;
    };
    unsigned long long* packed = (unsigned long long*)alloc((size_t)N * 8);
    float*  dinv = (float*)alloc((size_t)N * 4);
    int*    cnt  = (int*)  alloc((size_t)N * 4);
    int*    bsum = (int*)  alloc(1024);
    int*    boff = (int*)  alloc(1024);
    int*    rp   = (int*)  alloc((size_t)(N + 1) * 4);
    int*    loc  = (int*)  alloc((size_t)E * 4);
    float2* ev   = (float2*)alloc((size_t)E * 8);
    __half* y16  = (__half*)alloc((size_t)N * D * 2);
    __half* z16  = (__half*)alloc((size_t)N * D * 2);

    int nbN = (N + 255) / 256;      // 196 (<= 256 for k_scan_b)
    int nbE = (E + 255) / 256;

    k_init<<<nbN, 256, 0, stream>>>(packed, N);
    k_edge_pass1<<<nbE, 256, 0, stream>>>(ei + E, ew, packed, loc, E);
    k_dinv<<<nbN, 256, 0, stream>>>(packed, dinv, cnt, N);
    k_scan_a<<<nbN, 256, 0, stream>>>(cnt, bsum, N);
    k_scan_b<<<1, 256, 0, stream>>>(bsum, boff, nbN);
    k_scan_c<<<nbN, 256, 0, stream>>>(cnt, boff, rp, N, E);
    k_fill<<<nbE, 256, 0, stream>>>(ei, ew, dinv, rp, loc, ev, E);

    int gg = (N + 127) / 128;   // 391 GEMM blocks
    int ga = (N + 3) / 4;       // agg blocks (4 waves each)

    k_gemm_mfma<true ><<<gg, 256, 0, stream>>>(x,   W1, nullptr, nullptr, y16, N);
    k_agg<<<ga, 256, 0, stream>>>(y16, rp, ev, dinv, b1, z16, N, 1);
    k_gemm_mfma<false><<<gg, 256, 0, stream>>>(z16, W2, nullptr, nullptr, y16, N);
    k_agg<<<ga, 256, 0, stream>>>(y16, rp, ev, dinv, b2, z16, N, 1);
    k_gemm_mfma<false><<<gg, 256, 0, stream>>>(z16, W3, nullptr, nullptr, y16, N);
    k_agg<<<ga, 256, 0, stream>>>(y16, rp, ev, dinv, b3, z16, N, 0);
    k_gemm_mfma<false><<<gg, 256, 0, stream>>>(z16, Wl, bl, (float*)d_out, nullptr, N);
}

// Round 7
// 305.049 us; speedup vs baseline: 26.0995x; 1.0157x over previous
//
#include <hip/hip_runtime.h>
#include <hip/hip_fp16.h>

// ---------------------------------------------------------------------------
// 3-layer GCN + linear head.  N=50000 nodes, E=800000 edges, D=128.
// Normalization factored: GEMM writes y16 = dinv*(z@W); CSR stores raw w
// (4 B packed); agg: out = b + dinv_i*(y16_i + sum w*y16_src).
// CSR build: padded u32 atomic (1 counter / 64 B line) -> scan -> fill;
// weighted degree via CSR sum (no fixed-point atomics).
// ---------------------------------------------------------------------------

#define D 128

typedef __attribute__((ext_vector_type(8))) _Float16 half8;
typedef __attribute__((ext_vector_type(4))) float floatx4;

#define CNT_STRIDE 16   // one u32 counter per 64 B cache line

// ---- pass 1: count edges per dst; old count -> per-edge CSR slot ----------
__global__ __launch_bounds__(256) void k_edge_pass1(const int* __restrict__ dst,
                                                    unsigned int* __restrict__ cntp,
                                                    int* __restrict__ loc, int E) {
    int e = blockIdx.x * 256 + threadIdx.x;
    if (e < E) {
        int d = dst[e];
        loc[e] = (int)atomicAdd(&cntp[(size_t)d * CNT_STRIDE], 1u);
    }
}

// ---- block-wide exclusive scan helper (256 threads) -----------------------
__device__ inline int block_exscan_256(int v) {
    int tid = threadIdx.x;
    int lane = tid & 63, wv = tid >> 6;
    int incl = v;
#pragma unroll
    for (int d = 1; d < 64; d <<= 1) {
        int n = __shfl_up(incl, d, 64);
        if (lane >= d) incl += n;
    }
    __shared__ int wsum[4];
    if (lane == 63) wsum[wv] = incl;
    __syncthreads();
    int woff = 0;
#pragma unroll
    for (int j = 0; j < 4; j++) woff += (j < wv) ? wsum[j] : 0;
    return woff + incl - v;
}

__global__ __launch_bounds__(256) void k_scan_a(const unsigned int* __restrict__ cntp,
                                                int* bsum, int N) {
    int i = blockIdx.x * 256 + threadIdx.x;
    int v = (i < N) ? (int)cntp[(size_t)i * CNT_STRIDE] : 0;
#pragma unroll
    for (int d = 32; d; d >>= 1) v += __shfl_down(v, d, 64);
    __shared__ int ws4[4];
    int lane = threadIdx.x & 63, wv = threadIdx.x >> 6;
    if (lane == 0) ws4[wv] = v;
    __syncthreads();
    if (threadIdx.x == 0) bsum[blockIdx.x] = ws4[0] + ws4[1] + ws4[2] + ws4[3];
}

__global__ __launch_bounds__(256) void k_scan_b(const int* __restrict__ bsum,
                                                int* boff, int nb) {
    int tid = threadIdx.x;
    int v = (tid < nb) ? bsum[tid] : 0;
    int ex = block_exscan_256(v);
    if (tid < nb) boff[tid] = ex;
}

__global__ __launch_bounds__(256) void k_scan_c(const unsigned int* __restrict__ cntp,
                                                const int* __restrict__ boff,
                                                int* rp, int N, int E) {
    int i = blockIdx.x * 256 + threadIdx.x;
    int v = (i < N) ? (int)cntp[(size_t)i * CNT_STRIDE] : 0;
    int ex = block_exscan_256(v);
    if (i < N) rp[i] = boff[blockIdx.x] + ex;
    if (i == 0) rp[N] = E;
}

// ---- CSR fill: ev[p] = (w_q15 << 17) | src  (4 B per edge, no gathers) ----
__global__ __launch_bounds__(256) void k_fill(const int* __restrict__ ei,
                                              const float* __restrict__ w,
                                              const int* __restrict__ rp,
                                              const int* __restrict__ loc,
                                              unsigned int* __restrict__ ev, int E) {
    int e = blockIdx.x * 256 + threadIdx.x;
    if (e < E) {
        int s = ei[e];
        int d = ei[E + e];
        int p = rp[d] + loc[e];
        unsigned int wq = (unsigned int)__float2uint_rn(w[e] * 32767.0f);
        ev[p] = (wq << 17) | (unsigned int)s;
    }
}

// ---- weighted degree from CSR; dinv = rsqrt(1 + sum w) --------------------
__global__ __launch_bounds__(256) void k_deg(const int* __restrict__ rp,
                                             const unsigned int* __restrict__ ev,
                                             float* __restrict__ dinv, int N) {
    int i = blockIdx.x * 256 + threadIdx.x;
    if (i < N) {
        int e0 = rp[i], e1 = rp[i + 1];
        float s = 0.f;
        for (int e = e0; e < e1; e++)
            s += (float)(ev[e] >> 17);
        dinv[i] = rsqrtf(1.0f + s * (1.0f / 32767.0f));
    }
}

// ---- MFMA GEMM: y = A @ W ; optional row scale by dinv; optional bias -----
// 128 rows/block (4 waves x 32 rows), v_mfma_f32_16x16x32_f16, fp32 accum.
// W staged transposed as fp16 in LDS (Wl[n][k], pad->136). A fragments from
// global (read exactly once). Layouts (m89/m91): A[m=lane&15][k=quad*8+j],
// B[k=quad*8+j][n=lane&15], C/D col=lane&15, row=quad*4+reg.
template <bool A_IS_F32>
__global__ __launch_bounds__(256) void k_gemm_mfma(const void* __restrict__ Aptr,
                                                   const float* __restrict__ W,
                                                   const float* __restrict__ dinv,
                                                   const float* __restrict__ bias,
                                                   float* __restrict__ C32,
                                                   __half* __restrict__ C16, int N) {
    __shared__ _Float16 Wl[128][136];
    int tid = threadIdx.x;

#pragma unroll
    for (int j = 0; j < 64; j++) {
        int e = tid + j * 256;          // 16384 elements
        int k = e >> 7, n = e & 127;
        Wl[n][k] = (_Float16)W[e];
    }
    __syncthreads();

    int wave = tid >> 6, lane = tid & 63;
    int m = lane & 15, q = lane >> 4;
    int R0 = blockIdx.x * 128 + wave * 32;   // row tiles R0, R0+16

    const float*  A32p = (const float*)Aptr;
    const __half* A16p = (const __half*)Aptr;

    floatx4 acc[2][8];
#pragma unroll
    for (int rt = 0; rt < 2; rt++)
#pragma unroll
        for (int ct = 0; ct < 8; ct++) acc[rt][ct] = (floatx4){0.f, 0.f, 0.f, 0.f};

#pragma unroll
    for (int kk = 0; kk < 4; kk++) {
        half8 a[2];
#pragma unroll
        for (int rt = 0; rt < 2; rt++) {
            int row = R0 + rt * 16 + m;
            half8 t = {0, 0, 0, 0, 0, 0, 0, 0};
            if (row < N) {
                if (A_IS_F32) {
                    const float* p = &A32p[(size_t)row * 128 + kk * 32 + q * 8];
                    float4 f0 = *(const float4*)p;
                    float4 f1 = *(const float4*)(p + 4);
                    t[0] = (_Float16)f0.x; t[1] = (_Float16)f0.y;
                    t[2] = (_Float16)f0.z; t[3] = (_Float16)f0.w;
                    t[4] = (_Float16)f1.x; t[5] = (_Float16)f1.y;
                    t[6] = (_Float16)f1.z; t[7] = (_Float16)f1.w;
                } else {
                    t = *(const half8*)&A16p[(size_t)row * 128 + kk * 32 + q * 8];
                }
            }
            a[rt] = t;
        }
#pragma unroll
        for (int ct = 0; ct < 8; ct++) {
            half8 b = *(const half8*)&Wl[ct * 16 + m][kk * 32 + q * 8];
            acc[0][ct] = __builtin_amdgcn_mfma_f32_16x16x32_f16(a[0], b, acc[0][ct], 0, 0, 0);
            acc[1][ct] = __builtin_amdgcn_mfma_f32_16x16x32_f16(a[1], b, acc[1][ct], 0, 0, 0);
        }
    }

    // epilogue: C/D col=lane&15 (=m), row=quad*4+reg
#pragma unroll
    for (int rt = 0; rt < 2; rt++) {
#pragma unroll
        for (int r = 0; r < 4; r++) {
            int row = R0 + rt * 16 + q * 4 + r;
            if (row >= N) continue;
            float dv = (dinv != nullptr) ? dinv[row] : 1.0f;
#pragma unroll
            for (int ct = 0; ct < 8; ct++) {
                int col = ct * 16 + m;
                float v = acc[rt][ct][r] * dv;
                if (C16) C16[(size_t)row * 128 + col] = __float2half_rn(v);
                if (C32) C32[(size_t)row * 128 + col] = v + bias[col];
            }
        }
    }
}

// ---- aggregation: out_i = b + dinv_i*(y16_i + sum w*y16_src) --------------
// One wave per node; quarter-wave (16 lanes) per edge; lane sl=lane&15 covers
// features sl*8..sl*8+7 as one uint4 (8 fp16). 16 edges in flight per wave.
__global__ __launch_bounds__(256) void k_agg(const __half* __restrict__ y16,
                                             const int* __restrict__ rp,
                                             const unsigned int* __restrict__ ev,
                                             const float* __restrict__ dinv,
                                             const float* __restrict__ bias,
                                             __half* __restrict__ out16,
                                             int N, int relu) {
    int wave = blockIdx.x * 4 + (threadIdx.x >> 6);
    if (wave >= N) return;
    int lane = threadIdx.x & 63;
    int g = lane >> 4;
    int sl = lane & 15;
    int i = wave;

    float acc[8];
#pragma unroll
    for (int j = 0; j < 8; j++) acc[j] = 0.f;

    int e0 = rp[i], e1 = rp[i + 1];
    int e = e0;

#define GFMA(Q, V)                                                        \
    {                                                                     \
        union { uint4 u; __half2 h2[4]; } U; U.u = (Q);                   \
        float2 f0 = __half22float2(U.h2[0]);                              \
        float2 f1 = __half22float2(U.h2[1]);                              \
        float2 f2 = __half22float2(U.h2[2]);                              \
        float2 f3 = __half22float2(U.h2[3]);                              \
        acc[0] = fmaf(V, f0.x, acc[0]); acc[1] = fmaf(V, f0.y, acc[1]);   \
        acc[2] = fmaf(V, f1.x, acc[2]); acc[3] = fmaf(V, f1.y, acc[3]);   \
        acc[4] = fmaf(V, f2.x, acc[4]); acc[5] = fmaf(V, f2.y, acc[5]);   \
        acc[6] = fmaf(V, f3.x, acc[6]); acc[7] = fmaf(V, f3.y, acc[7]);   \
    }
#define UNPK(P, C, V)                                                     \
    int   C = (int)((P) & 0x1FFFFu);                                      \
    float V = (float)((P) >> 17) * (1.0f / 32767.0f);

    for (; e + 16 <= e1; e += 16) {
        unsigned int pA = ev[e + g];
        unsigned int pB = ev[e + 4 + g];
        unsigned int pC = ev[e + 8 + g];
        unsigned int pD = ev[e + 12 + g];
        UNPK(pA, cA, vA); UNPK(pB, cB, vB); UNPK(pC, cC, vC); UNPK(pD, cD, vD);
        uint4 qA = *(const uint4*)&y16[(size_t)cA * D + sl * 8];
        uint4 qB = *(const uint4*)&y16[(size_t)cB * D + sl * 8];
        uint4 qC = *(const uint4*)&y16[(size_t)cC * D + sl * 8];
        uint4 qD = *(const uint4*)&y16[(size_t)cD * D + sl * 8];
        GFMA(qA, vA); GFMA(qB, vB); GFMA(qC, vC); GFMA(qD, vD);
    }
    if (e + 8 <= e1) {
        unsigned int pA = ev[e + g];
        unsigned int pB = ev[e + 4 + g];
        UNPK(pA, cA, vA); UNPK(pB, cB, vB);
        uint4 qA = *(const uint4*)&y16[(size_t)cA * D + sl * 8];
        uint4 qB = *(const uint4*)&y16[(size_t)cB * D + sl * 8];
        GFMA(qA, vA); GFMA(qB, vB);
        e += 8;
    }
    if (e + 4 <= e1) {
        unsigned int pA = ev[e + g];
        UNPK(pA, cA, vA);
        uint4 qA = *(const uint4*)&y16[(size_t)cA * D + sl * 8];
        GFMA(qA, vA);
        e += 4;
    }
    if (e + g < e1) {
        unsigned int pA = ev[e + g];
        UNPK(pA, cA, vA);
        uint4 qA = *(const uint4*)&y16[(size_t)cA * D + sl * 8];
        GFMA(qA, vA);
    }
#undef UNPK
#undef GFMA

    // fold the 4 quarter-wave partials (lane ^16, ^32)
#pragma unroll
    for (int j = 0; j < 8; j++) {
        acc[j] += __shfl_xor(acc[j], 16, 64);
        acc[j] += __shfl_xor(acc[j], 32, 64);
    }

    if (g == 0) {
        float di = dinv[i];
        union { uint4 u; __half2 h2[4]; } S;
        S.u = *(const uint4*)&y16[(size_t)i * D + sl * 8];
        float2 s0 = __half22float2(S.h2[0]);
        float2 s1 = __half22float2(S.h2[1]);
        float2 s2 = __half22float2(S.h2[2]);
        float2 s3 = __half22float2(S.h2[3]);
        float4 b0 = *(const float4*)&bias[sl * 8];
        float4 b1 = *(const float4*)&bias[sl * 8 + 4];
        float o[8];
        o[0] = b0.x + di * (acc[0] + s0.x);
        o[1] = b0.y + di * (acc[1] + s0.y);
        o[2] = b0.z + di * (acc[2] + s1.x);
        o[3] = b0.w + di * (acc[3] + s1.y);
        o[4] = b1.x + di * (acc[4] + s2.x);
        o[5] = b1.y + di * (acc[5] + s2.y);
        o[6] = b1.z + di * (acc[6] + s3.x);
        o[7] = b1.w + di * (acc[7] + s3.y);
        if (relu) {
#pragma unroll
            for (int j = 0; j < 8; j++) o[j] = fmaxf(o[j], 0.f);
        }
        union { uint4 u; __half2 h2[4]; } O;
        O.h2[0] = __float22half2_rn(make_float2(o[0], o[1]));
        O.h2[1] = __float22half2_rn(make_float2(o[2], o[3]));
        O.h2[2] = __float22half2_rn(make_float2(o[4], o[5]));
        O.h2[3] = __float22half2_rn(make_float2(o[6], o[7]));
        *(uint4*)&out16[(size_t)i * D + sl * 8] = O.u;
    }
}

// ---------------------------------------------------------------------------
extern "C" void kernel_launch(void* const* d_in, const int* in_sizes, int n_in,
                              void* d_out, int out_size, void* d_ws, size_t ws_size,
                              hipStream_t stream) {
    const float* x  = (const float*)d_in[0];
    const int*   ei = (const int*)d_in[1];     // [2,E]: src row then dst row
    const float* ew = (const float*)d_in[2];
    const float* W1 = (const float*)d_in[3];
    const float* b1 = (const float*)d_in[4];
    const float* W2 = (const float*)d_in[5];
    const float* b2 = (const float*)d_in[6];
    const float* W3 = (const float*)d_in[7];
    const float* b3 = (const float*)d_in[8];
    const float* Wl = (const float*)d_in[9];
    const float* bl = (const float*)d_in[10];

    int N = in_sizes[0] / D;    // 50000
    int E = in_sizes[2];        // 800000

    char* ws = (char*)d_ws;
    size_t off = 0;
    auto alloc = [&](size_t bytes) {
        void* p = ws + off;
        off = (off + bytes + 255) & ~(size_t)255;
        return p;
    };
    unsigned int* cntp = (unsigned int*)alloc((size_t)N * CNT_STRIDE * 4); // 3.2 MB
    float*  dinv = (float*)alloc((size_t)N * 4);
    int*    bsum = (int*)  alloc(1024);
    int*    boff = (int*)  alloc(1024);
    int*    rp   = (int*)  alloc((size_t)(N + 1) * 4);
    int*    loc  = (int*)  alloc((size_t)E * 4);
    unsigned int* ev = (unsigned int*)alloc((size_t)E * 4);
    __half* y16  = (__half*)alloc((size_t)N * D * 2);
    __half* z16  = (__half*)alloc((size_t)N * D * 2);

    int nbN = (N + 255) / 256;      // 196 (<= 256 for k_scan_b)
    int nbE = (E + 255) / 256;

    hipMemsetAsync(cntp, 0, (size_t)N * CNT_STRIDE * 4, stream);
    k_edge_pass1<<<nbE, 256, 0, stream>>>(ei + E, cntp, loc, E);
    k_scan_a<<<nbN, 256, 0, stream>>>(cntp, bsum, N);
    k_scan_b<<<1, 256, 0, stream>>>(bsum, boff, nbN);
    k_scan_c<<<nbN, 256, 0, stream>>>(cntp, boff, rp, N, E);
    k_fill<<<nbE, 256, 0, stream>>>(ei, ew, rp, loc, ev, E);
    k_deg<<<nbN, 256, 0, stream>>>(rp, ev, dinv, N);

    int gg = (N + 127) / 128;   // 391 GEMM blocks
    int ga = (N + 3) / 4;       // agg blocks (4 waves each)

    k_gemm_mfma<true ><<<gg, 256, 0, stream>>>(x,   W1, dinv, nullptr, nullptr, y16, N);
    k_agg<<<ga, 256, 0, stream>>>(y16, rp, ev, dinv, b1, z16, N, 1);
    k_gemm_mfma<false><<<gg, 256, 0, stream>>>(z16, W2, dinv, nullptr, nullptr, y16, N);
    k_agg<<<ga, 256, 0, stream>>>(y16, rp, ev, dinv, b2, z16, N, 1);
    k_gemm_mfma<false><<<gg, 256, 0, stream>>>(z16, W3, dinv, nullptr, nullptr, y16, N);
    k_agg<<<ga, 256, 0, stream>>>(y16, rp, ev, dinv, b3, z16, N, 0);
    k_gemm_mfma<false><<<gg, 256, 0, stream>>>(z16, Wl, nullptr, bl, (float*)d_out, nullptr, N);
}